// Round 5
// baseline (663.445 us; speedup 1.0000x reference)
//
#include <hip/hip_runtime.h>

typedef __attribute__((ext_vector_type(8))) short short8;
typedef __attribute__((ext_vector_type(4))) float floatx4;

#define MFMA16(a,b,c) __builtin_amdgcn_mfma_f32_16x16x32_bf16(a,b,c,0,0,0)

__device__ __forceinline__ unsigned short f2bf(float f){
  unsigned u = __float_as_uint(f);
  u += 0x7fffu + ((u >> 16) & 1u);
  return (unsigned short)(u >> 16);
}
__device__ __forceinline__ float sigm(float x){ return 1.f/(1.f+__expf(-x)); }

// WhB/WgA swizzled B/A-fragment layouts:
//  element (o, m):  flat = (o>>4)*32768 + (m>>5)*512 + (((m>>3)&3)*16 + (o&15))*8 + (m&7)
//  -> a wave's 64 lanes (lane = quad*16+l16) read 1KB contiguous per (o16, m32) chunk.

// ---- fused prep: cell init + WgA swizzle + cwT transpose + adjacency bitmasks ----
__global__ __launch_bounds__(256) void prep_kernel(const float* __restrict__ actors,
    const float* __restrict__ Wg, const float* __restrict__ cw, const int* __restrict__ adj,
    float* __restrict__ cell, unsigned short* __restrict__ WgA, float* __restrict__ cwT,
    unsigned long long* __restrict__ bm){
  int bid = blockIdx.x;
  if (bid < 1024){
    int idx = bid*256 + threadIdx.x;
    int n = idx >> 7, c = idx & 127;
    cell[idx] = actors[(size_t)n*2560 + c];
  } else if (bid < 1536){
    int e = (bid-1024)*256 + threadIdx.x;            // 131072
    int g = e >> 15, o = (e >> 8) & 127, k = e & 255;
    unsigned short v = f2bf(Wg[(size_t)g*32768 + k*128 + o]);
    int off = ((o>>4)*8 + (k>>5))*512 + (((k>>3)&3)*16 + (o&15))*8 + (k&7);
    WgA[(size_t)g*32768 + off] = v;
  } else if (bid < 1728){
    int e = (bid-1536)*256 + threadIdx.x;            // 49152
    int l = e >> 14, rr = e & 16383, k = rr >> 7, o = rr & 127;
    cwT[(size_t)l*32768 + k*256 + o]       = cw[(size_t)l*32768 + o*256 + k*2];
    cwT[(size_t)l*32768 + k*256 + 128 + o] = cw[(size_t)l*32768 + o*256 + k*2 + 1];
  } else {
    const int E[4] = {0,4,9,14};
    int mb = bid - 1728;                             // 2048 blocks
    int t = mb & 3, nblk = mb >> 2;
    int wv = threadIdx.x >> 6, lane = threadIdx.x & 63;
    int n = nblk*4 + wv;
    const int* row = adj + (size_t)n*40960 + (size_t)E[t]*2048;
    unsigned long long* outp = bm + ((size_t)t*2048 + n)*32;
    for (int it=0; it<32; ++it){
      unsigned long long bal = __ballot(row[it*64 + lane] > 0);
      if (lane == 0) outp[it] = bal;
    }
  }
}

// ---- fused: LSTM gate (from gbuf_{t-1}) + y-plane outproj + 4-gate Wh GEMM ----
// grid 128 x 256 threads; 16 rows per block.
__global__ __launch_bounds__(256) void gatewh_kernel(const float* __restrict__ actors,
    const float* __restrict__ gbuf, float* __restrict__ cell, const float* __restrict__ h0,
    const float* __restrict__ W, const float* __restrict__ bvec,
    const unsigned short* __restrict__ WgA, const float* __restrict__ ag,
    float* __restrict__ y, unsigned short* __restrict__ WhB,
    float* __restrict__ s_src, float* __restrict__ s_dst, int xoff, int t){
  __shared__ float hl[16][132];
  __shared__ __align__(16) unsigned short ginb[16*264];
  __shared__ float sredS[4][4][16], sredD[4][4][16];
  int n0 = blockIdx.x*16, tid = threadIdx.x;
  int row = tid>>4, o0 = (tid&15)*8;
  // Phase A: hidden (+cell, from previous gates)
  if (t == 0){
    const float* hp = h0 + o0;
    #pragma unroll
    for (int j=0;j<8;++j) hl[row][o0+j] = hp[j];
  } else {
    size_t idx = (size_t)(n0+row)*128 + o0;
    float4 ga0 = *(const float4*)(gbuf+idx),          ga1 = *(const float4*)(gbuf+idx+4);
    float4 gb0 = *(const float4*)(gbuf+262144+idx),   gb1 = *(const float4*)(gbuf+262144+idx+4);
    float4 gc0 = *(const float4*)(gbuf+524288+idx),   gc1 = *(const float4*)(gbuf+524288+idx+4);
    float4 gd0 = *(const float4*)(gbuf+786432+idx),   gd1 = *(const float4*)(gbuf+786432+idx+4);
    float4 c0 = *(const float4*)(cell+idx),           c1 = *(const float4*)(cell+idx+4);
    float fgv[8] = {ga0.x,ga0.y,ga0.z,ga0.w,ga1.x,ga1.y,ga1.z,ga1.w};
    float igv[8] = {gb0.x,gb0.y,gb0.z,gb0.w,gb1.x,gb1.y,gb1.z,gb1.w};
    float icv[8] = {gc0.x,gc0.y,gc0.z,gc0.w,gc1.x,gc1.y,gc1.z,gc1.w};
    float ogv[8] = {gd0.x,gd0.y,gd0.z,gd0.w,gd1.x,gd1.y,gd1.z,gd1.w};
    float cv[8]  = {c0.x,c0.y,c0.z,c0.w,c1.x,c1.y,c1.z,c1.w};
    float cl[8], hd[8];
    #pragma unroll
    for (int j=0;j<8;++j){
      cl[j] = cv[j]*sigm(fgv[j]) + sigm(igv[j])*tanhf(icv[j]);
      hd[j] = tanhf(cl[j])*sigm(ogv[j]);
      hl[row][o0+j] = hd[j];
    }
    *(float4*)(cell+idx)   = (float4){cl[0],cl[1],cl[2],cl[3]};
    *(float4*)(cell+idx+4) = (float4){cl[4],cl[5],cl[6],cl[7]};
  }
  __syncthreads();
  // outproj y plane t-1
  if (t >= 1){
    float acc[8];
    float4 b0 = *(const float4*)(bvec+o0), b1 = *(const float4*)(bvec+o0+4);
    acc[0]=b0.x;acc[1]=b0.y;acc[2]=b0.z;acc[3]=b0.w;acc[4]=b1.x;acc[5]=b1.y;acc[6]=b1.z;acc[7]=b1.w;
    for (int k=0;k<128;++k){
      float hv = hl[row][k];
      float4 w0 = *(const float4*)(W + (size_t)k*128 + o0);
      float4 w1 = *(const float4*)(W + (size_t)k*128 + o0 + 4);
      acc[0]+=hv*w0.x; acc[1]+=hv*w0.y; acc[2]+=hv*w0.z; acc[3]+=hv*w0.w;
      acc[4]+=hv*w1.x; acc[5]+=hv*w1.y; acc[6]+=hv*w1.z; acc[7]+=hv*w1.w;
    }
    float* yp = y + (size_t)(t-1)*262144 + (size_t)(n0+row)*128 + o0;
    #pragma unroll
    for (int j=0;j<8;++j) yp[j] = sigm(acc[j]);
  }
  // Phase B: gin bf16 = [X | hidden]
  {
    const float* ap = actors + (size_t)(n0+row)*2560 + xoff + o0;
    float4 a = *(const float4*)ap, bb = *(const float4*)(ap+4);
    unsigned short tmp[8] = {f2bf(a.x),f2bf(a.y),f2bf(a.z),f2bf(a.w),
                             f2bf(bb.x),f2bf(bb.y),f2bf(bb.z),f2bf(bb.w)};
    *(uint4*)&ginb[row*264 + o0] = *(const uint4*)tmp;
    unsigned short tmp2[8];
    #pragma unroll
    for (int j=0;j<8;++j) tmp2[j] = f2bf(hl[row][o0+j]);
    *(uint4*)&ginb[row*264 + 128 + o0] = *(const uint4*)tmp2;
  }
  __syncthreads();
  // Phase C: 4-gate GEMM, wave w -> o in [w*32, w*32+32)
  int w = tid>>6, lane = tid&63, quad = lane>>4, l16 = lane&15;
  int m32 = blockIdx.x>>1, min32 = (blockIdx.x&1)*16 + l16;
  int qp = min32>>3, jp = min32&7;
  for (int g=0; g<4; ++g){
    floatx4 acc0 = {0.f,0.f,0.f,0.f}, acc1 = acc0;
    const unsigned short* wa = WgA + (size_t)g*32768;
    #pragma unroll
    for (int kh=0; kh<8; ++kh){
      short8 bfr = *(const short8*)&ginb[l16*264 + kh*32 + quad*8];
      short8 a0 = *(const short8*)(wa + (size_t)(((w*2+0)*8 + kh)*64 + lane)*8);
      short8 a1 = *(const short8*)(wa + (size_t)(((w*2+1)*8 + kh)*64 + lane)*8);
      acc0 = MFMA16(a0, bfr, acc0);
      acc1 = MFMA16(a1, bfr, acc1);
    }
    float ps = 0.f, pd = 0.f;
    unsigned short* wb = WhB + (size_t)(g*8 + w*2)*32768 + m32*512 + qp*128 + jp;
    const float* agp = ag + g*256;
    #pragma unroll
    for (int i=0;i<2;++i){
      floatx4 ac = i ? acc1 : acc0;
      #pragma unroll
      for (int r=0;r<4;++r){
        int o = w*32 + i*16 + quad*4 + r;
        float v = ac[r];
        ps += v*agp[o]; pd += v*agp[128+o];
        wb[i*32768 + (quad*4+r)*8] = f2bf(v);
      }
    }
    ps += __shfl_down(ps,32); ps += __shfl_down(ps,16);
    pd += __shfl_down(pd,32); pd += __shfl_down(pd,16);
    if (lane < 16){ sredS[g][w][l16] = ps; sredD[g][w][l16] = pd; }
  }
  __syncthreads();
  if (tid < 128){
    int g = tid>>5, which = (tid>>4)&1, n = tid&15;
    float s;
    if (which) s = sredD[g][0][n]+sredD[g][1][n]+sredD[g][2][n]+sredD[g][3][n];
    else       s = sredS[g][0][n]+sredS[g][1][n]+sredS[g][2][n]+sredS[g][3][n];
    (which ? s_dst : s_src)[g*2048 + n0 + n] = s;
  }
}

// ---- fused masked-softmax + PV: 256 thr = 4 m-waves, 32 rows/wave, full-o ----
// Two 16-row A-fragments per wave share every B-fragment load (halves L2 traffic).
__global__ __launch_bounds__(256) void attn_kernel(const unsigned char* __restrict__ bmb,
    const unsigned short* __restrict__ WhB, const float* __restrict__ s_src,
    const float* __restrict__ s_dst, float* __restrict__ gout, int t){
  __shared__ float obuf[2][32][132];   // 33.8 KB
  __shared__ float zpart[4][32];
  int g = blockIdx.y, n0 = blockIdx.x*32, tid = threadIdx.x;
  int w = tid>>6, lane = tid&63, quad = lane>>4, l16 = lane&15;
  float srcv0 = s_src[g*2048 + n0 + l16];
  float srcv1 = s_src[g*2048 + n0 + 16 + l16];
  const float* sd = s_dst + g*2048;
  // preload both rows' 64-byte mask strips (m in [w*512, w*512+512))
  const unsigned char* mr0 = bmb + ((size_t)t*2048 + n0 + l16)*256 + w*64;
  const unsigned char* mr1 = mr0 + 16*256;
  uint4 q0 = *(const uint4*)mr0,      q1 = *(const uint4*)(mr0+16);
  uint4 q2 = *(const uint4*)(mr0+32), q3 = *(const uint4*)(mr0+48);
  uint4 r0 = *(const uint4*)mr1,      r1 = *(const uint4*)(mr1+16);
  uint4 r2 = *(const uint4*)(mr1+32), r3 = *(const uint4*)(mr1+48);
  unsigned mwd0[16] = {q0.x,q0.y,q0.z,q0.w, q1.x,q1.y,q1.z,q1.w,
                       q2.x,q2.y,q2.z,q2.w, q3.x,q3.y,q3.z,q3.w};
  unsigned mwd1[16] = {r0.x,r0.y,r0.z,r0.w, r1.x,r1.y,r1.z,r1.w,
                       r2.x,r2.y,r2.z,r2.w, r3.x,r3.y,r3.z,r3.w};
  const unsigned short* wb = WhB + (size_t)g*262144;
  float z0 = 0.f, z1 = 0.f;
  floatx4 acc0[8], acc1[8];
  #pragma unroll
  for (int j=0;j<8;++j){ acc0[j] = (floatx4){0.f,0.f,0.f,0.f}; acc1[j] = acc0[j]; }
  #pragma unroll
  for (int c=0; c<16; ++c){
    int mk = w*512 + c*32 + quad*8;
    float4 sa = *(const float4*)(sd + mk);
    float4 sb = *(const float4*)(sd + mk + 4);
    unsigned mb0 = (mwd0[c] >> (quad*8)) & 0xffu;
    unsigned mb1 = (mwd1[c] >> (quad*8)) & 0xffu;
    float sv[8] = {sa.x,sa.y,sa.z,sa.w,sb.x,sb.y,sb.z,sb.w};
    short8 A0, A1;
    #pragma unroll
    for (int j=0;j<8;++j){
      float s0 = srcv0 + sv[j];
      s0 = s0 > 0.f ? s0 : 0.2f*s0;                // leaky_relu
      float p0 = ((mb0 >> j) & 1u) ? __expf(s0) : 0.f;
      z0 += p0;
      A0[j] = (short)f2bf(p0);
      float s1 = srcv1 + sv[j];
      s1 = s1 > 0.f ? s1 : 0.2f*s1;
      float p1 = ((mb1 >> j) & 1u) ? __expf(s1) : 0.f;
      z1 += p1;
      A1[j] = (short)f2bf(p1);
    }
    const unsigned short* bp = wb + (size_t)(w*16 + c)*512 + lane*8;
    #pragma unroll
    for (int o16=0; o16<8; ++o16){
      short8 bfr = *(const short8*)(bp + (size_t)o16*32768);
      acc0[o16] = MFMA16(A0, bfr, acc0[o16]);
      acc1[o16] = MFMA16(A1, bfr, acc1[o16]);
    }
  }
  z0 += __shfl_down(z0,32); z0 += __shfl_down(z0,16);
  z1 += __shfl_down(z1,32); z1 += __shfl_down(z1,16);
  if (lane < 16){ zpart[w][l16] = z0; zpart[w][16+l16] = z1; }
  if (w < 2){
    #pragma unroll
    for (int o16=0;o16<8;++o16)
      #pragma unroll
      for (int r=0;r<4;++r){
        obuf[w][quad*4+r][o16*16+l16]    = acc0[o16][r];
        obuf[w][16+quad*4+r][o16*16+l16] = acc1[o16][r];
      }
  }
  __syncthreads();
  if (w >= 2){
    #pragma unroll
    for (int o16=0;o16<8;++o16)
      #pragma unroll
      for (int r=0;r<4;++r){
        obuf[w-2][quad*4+r][o16*16+l16]    += acc0[o16][r];
        obuf[w-2][16+quad*4+r][o16*16+l16] += acc1[o16][r];
      }
  }
  __syncthreads();
  { // normalize + elu + store: 16 floats/thread
    int row = tid>>3, c0 = (tid&7)*16;
    float z = zpart[0][row]+zpart[1][row]+zpart[2][row]+zpart[3][row];
    float inv = 1.f / z;
    float* go = gout + (size_t)g*262144 + (size_t)(n0+row)*128 + c0;
    #pragma unroll
    for (int j=0;j<16;++j){
      float v = (obuf[0][row][c0+j] + obuf[1][row][c0+j]) * inv;
      go[j] = v > 0.f ? v : __expf(v) - 1.f;       // elu
    }
  }
}

// ---- final gate + y3 + all 3 temporal conv layers; 8 rows/block ----
__global__ __launch_bounds__(256) void convgate_kernel(const float* __restrict__ gbuf,
    const float* __restrict__ cell, const float* __restrict__ W, const float* __restrict__ bvec,
    const float* __restrict__ y, const float* __restrict__ cwT, const float* __restrict__ cb,
    float* __restrict__ out){
  __shared__ float hl[8][128];
  __shared__ float ylds[8][128][4];
  int tid = threadIdx.x;
  int r = tid >> 5, o0 = (tid & 31)*4;
  int n = blockIdx.x*8 + r;
  size_t idx = (size_t)n*128 + o0;
  { // gate_3
    float4 g0 = *(const float4*)(gbuf+idx),        g1 = *(const float4*)(gbuf+262144+idx);
    float4 g2 = *(const float4*)(gbuf+524288+idx), g3 = *(const float4*)(gbuf+786432+idx);
    float4 cv = *(const float4*)(cell+idx);
    float fg[4]={g0.x,g0.y,g0.z,g0.w}, ig[4]={g1.x,g1.y,g1.z,g1.w};
    float ic[4]={g2.x,g2.y,g2.z,g2.w}, og[4]={g3.x,g3.y,g3.z,g3.w};
    float cc[4]={cv.x,cv.y,cv.z,cv.w};
    #pragma unroll
    for (int j=0;j<4;++j){
      float cl = cc[j]*sigm(fg[j]) + sigm(ig[j])*tanhf(ic[j]);
      hl[r][o0+j] = tanhf(cl)*sigm(og[j]);
    }
  }
  {
    float4 y0 = *(const float4*)(y+idx), y1 = *(const float4*)(y+262144+idx),
           y2 = *(const float4*)(y+524288+idx);
    float a0[4]={y0.x,y0.y,y0.z,y0.w}, a1[4]={y1.x,y1.y,y1.z,y1.w}, a2[4]={y2.x,y2.y,y2.z,y2.w};
    #pragma unroll
    for (int j=0;j<4;++j){
      ylds[r][o0+j][0]=a0[j]; ylds[r][o0+j][1]=a1[j]; ylds[r][o0+j][2]=a2[j];
    }
  }
  __syncthreads();
  { // y3 outproj
    float4 bb = *(const float4*)(bvec+o0);
    float acc[4] = {bb.x,bb.y,bb.z,bb.w};
    const float* hr = hl[r];
    for (int k=0;k<128;++k){
      float hv = hr[k];
      float4 wv = *(const float4*)(W + (size_t)k*128 + o0);
      acc[0]+=hv*wv.x; acc[1]+=hv*wv.y; acc[2]+=hv*wv.z; acc[3]+=hv*wv.w;
    }
    #pragma unroll
    for (int j=0;j<4;++j) ylds[r][o0+j][3] = sigm(acc[j]);
  }
  __syncthreads();
  { // layer 0: 4 -> 3
    float a0[4]={0,0,0,0}, a1[4]={0,0,0,0}, a2[4]={0,0,0,0};
    for (int k=0;k<128;++k){
      float4 w0 = *(const float4*)(cwT + k*256 + o0);
      float4 w1 = *(const float4*)(cwT + k*256 + 128 + o0);
      float4 yv = *(const float4*)&ylds[r][k][0];
      float wa[4]={w0.x,w0.y,w0.z,w0.w}, wb4[4]={w1.x,w1.y,w1.z,w1.w};
      #pragma unroll
      for (int j=0;j<4;++j){
        a0[j] += yv.x*wa[j] + yv.y*wb4[j];
        a1[j] += yv.y*wa[j] + yv.z*wb4[j];
        a2[j] += yv.z*wa[j] + yv.w*wb4[j];
      }
    }
    float4 bb = *(const float4*)(cb+o0);
    float bbv[4]={bb.x,bb.y,bb.z,bb.w};
    __syncthreads();
    #pragma unroll
    for (int j=0;j<4;++j){
      ylds[r][o0+j][0]=a0[j]+bbv[j]; ylds[r][o0+j][1]=a1[j]+bbv[j]; ylds[r][o0+j][2]=a2[j]+bbv[j];
    }
    __syncthreads();
  }
  { // layer 1: 3 -> 2
    float a0[4]={0,0,0,0}, a1[4]={0,0,0,0};
    for (int k=0;k<128;++k){
      float4 w0 = *(const float4*)(cwT + 32768 + k*256 + o0);
      float4 w1 = *(const float4*)(cwT + 32768 + k*256 + 128 + o0);
      float4 yv = *(const float4*)&ylds[r][k][0];
      float wa[4]={w0.x,w0.y,w0.z,w0.w}, wb4[4]={w1.x,w1.y,w1.z,w1.w};
      #pragma unroll
      for (int j=0;j<4;++j){
        a0[j] += yv.x*wa[j] + yv.y*wb4[j];
        a1[j] += yv.y*wa[j] + yv.z*wb4[j];
      }
    }
    float4 bb = *(const float4*)(cb+128+o0);
    float bbv[4]={bb.x,bb.y,bb.z,bb.w};
    __syncthreads();
    #pragma unroll
    for (int j=0;j<4;++j){
      ylds[r][o0+j][0]=a0[j]+bbv[j]; ylds[r][o0+j][1]=a1[j]+bbv[j];
    }
    __syncthreads();
  }
  { // layer 2: 2 -> 1
    float a0[4]={0,0,0,0};
    for (int k=0;k<128;++k){
      float4 w0 = *(const float4*)(cwT + 65536 + k*256 + o0);
      float4 w1 = *(const float4*)(cwT + 65536 + k*256 + 128 + o0);
      float4 yv = *(const float4*)&ylds[r][k][0];
      float wa[4]={w0.x,w0.y,w0.z,w0.w}, wb4[4]={w1.x,w1.y,w1.z,w1.w};
      #pragma unroll
      for (int j=0;j<4;++j) a0[j] += yv.x*wa[j] + yv.y*wb4[j];
    }
    float4 bb = *(const float4*)(cb+256+o0);
    float4 res = {a0[0]+bb.x, a0[1]+bb.y, a0[2]+bb.z, a0[3]+bb.w};
    *(float4*)(out+idx) = res;
  }
}

extern "C" void kernel_launch(void* const* d_in, const int* in_sizes, int n_in,
                              void* d_out, int out_size, void* d_ws, size_t ws_size,
                              hipStream_t stream) {
  const float* actors = (const float*)d_in[0];
  const int*   adj    = (const int*)d_in[1];
  const float* Wg     = (const float*)d_in[2];
  const float* ag     = (const float*)d_in[3];
  const float* W      = (const float*)d_in[4];
  const float* b      = (const float*)d_in[5];
  const float* h0     = (const float*)d_in[6];
  const float* cw     = (const float*)d_in[7];
  const float* cb     = (const float*)d_in[8];
  float* out = (float*)d_out;

  char* ws = (char*)d_ws;
  unsigned long long* bm = (unsigned long long*)ws;                  // 2 MB
  float* cell          = (float*)(ws + (size_t)(2u<<20));            // 1 MB
  unsigned short* WgA  = (unsigned short*)(ws + (size_t)(3u<<20));   // 256 KB bf16 swizzled
  float* cwT           = (float*)(ws + (size_t)3407872);             // 384 KB
  float* s_src         = (float*)(ws + (size_t)3932160);             // 32 KB
  float* s_dst         = (float*)(ws + (size_t)3932160 + 32768);     // 32 KB
  unsigned short* WhB  = (unsigned short*)(ws + (size_t)(4u<<20));   // 2 MB bf16 swizzled
  float* gbuf          = (float*)(ws + (size_t)(7u<<20));            // 4 MB [g][n][o]
  float* yplanes       = (float*)(ws + (size_t)(11u<<20));           // 3 MB [t][n][o]

  const int XI[4] = {4, 9, 14, 19};

  prep_kernel<<<3776, 256, 0, stream>>>(actors, Wg, cw, adj, cell, WgA, cwT, bm);
  for (int t=0; t<4; ++t){
    gatewh_kernel<<<128, 256, 0, stream>>>(actors, gbuf, cell, h0, W, b, WgA, ag,
                                           yplanes, WhB, s_src, s_dst, XI[t]*128, t);
    attn_kernel<<<dim3(64,4), 256, 0, stream>>>((const unsigned char*)bm, WhB,
                                                s_src, s_dst, gbuf, t);
  }
  convgate_kernel<<<256, 256, 0, stream>>>(gbuf, cell, W, b, yplanes, cwT, cb, out);
}

// Round 6
// 600.126 us; speedup vs baseline: 1.1055x; 1.1055x over previous
//
#include <hip/hip_runtime.h>

typedef __attribute__((ext_vector_type(8))) short short8;
typedef __attribute__((ext_vector_type(4))) float floatx4;

#define MFMA16(a,b,c) __builtin_amdgcn_mfma_f32_16x16x32_bf16(a,b,c,0,0,0)

__device__ __forceinline__ unsigned short f2bf(float f){
  unsigned u = __float_as_uint(f);
  u += 0x7fffu + ((u >> 16) & 1u);
  return (unsigned short)(u >> 16);
}
__device__ __forceinline__ float sigm(float x){ return 1.f/(1.f+__expf(-x)); }

// WhB/WgA swizzled B/A-fragment layouts:
//  element (o, m):  flat = (o>>4)*32768 + (m>>5)*512 + (((m>>3)&3)*16 + (o&15))*8 + (m&7)
//  -> a wave's 64 lanes (lane = quad*16+l16) read 1KB contiguous per (o16, m32) chunk.

// ---- fused prep: cell init + WgA swizzle + cwT transpose + adjacency bitmasks ----
__global__ __launch_bounds__(256) void prep_kernel(const float* __restrict__ actors,
    const float* __restrict__ Wg, const float* __restrict__ cw, const int* __restrict__ adj,
    float* __restrict__ cell, unsigned short* __restrict__ WgA, float* __restrict__ cwT,
    unsigned long long* __restrict__ bm){
  int bid = blockIdx.x;
  if (bid < 1024){
    int idx = bid*256 + threadIdx.x;
    int n = idx >> 7, c = idx & 127;
    cell[idx] = actors[(size_t)n*2560 + c];
  } else if (bid < 1536){
    int e = (bid-1024)*256 + threadIdx.x;            // 131072
    int g = e >> 15, o = (e >> 8) & 127, k = e & 255;
    unsigned short v = f2bf(Wg[(size_t)g*32768 + k*128 + o]);
    int off = ((o>>4)*8 + (k>>5))*512 + (((k>>3)&3)*16 + (o&15))*8 + (k&7);
    WgA[(size_t)g*32768 + off] = v;
  } else if (bid < 1728){
    int e = (bid-1536)*256 + threadIdx.x;            // 49152
    int l = e >> 14, rr = e & 16383, k = rr >> 7, o = rr & 127;
    cwT[(size_t)l*32768 + k*256 + o]       = cw[(size_t)l*32768 + o*256 + k*2];
    cwT[(size_t)l*32768 + k*256 + 128 + o] = cw[(size_t)l*32768 + o*256 + k*2 + 1];
  } else {
    const int E[4] = {0,4,9,14};
    int mb = bid - 1728;                             // 2048 blocks
    int t = mb & 3, nblk = mb >> 2;
    int wv = threadIdx.x >> 6, lane = threadIdx.x & 63;
    int n = nblk*4 + wv;
    const int* row = adj + (size_t)n*40960 + (size_t)E[t]*2048;
    unsigned long long* outp = bm + ((size_t)t*2048 + n)*32;
    for (int it=0; it<32; ++it){
      unsigned long long bal = __ballot(row[it*64 + lane] > 0);
      if (lane == 0) outp[it] = bal;
    }
  }
}

// ---- fused: LSTM gate (from gbuf_{t-1}) + y-plane outproj + 4-gate Wh GEMM ----
// grid 128 x 256 threads; 16 rows per block.
__global__ __launch_bounds__(256) void gatewh_kernel(const float* __restrict__ actors,
    const float* __restrict__ gbuf, float* __restrict__ cell, const float* __restrict__ h0,
    const float* __restrict__ W, const float* __restrict__ bvec,
    const unsigned short* __restrict__ WgA, const float* __restrict__ ag,
    float* __restrict__ y, unsigned short* __restrict__ WhB,
    float* __restrict__ s_src, float* __restrict__ s_dst, int xoff, int t){
  __shared__ float hl[16][132];
  __shared__ __align__(16) unsigned short ginb[16*264];
  __shared__ float sredS[4][4][16], sredD[4][4][16];
  int n0 = blockIdx.x*16, tid = threadIdx.x;
  int row = tid>>4, o0 = (tid&15)*8;
  // Phase A: hidden (+cell, from previous gates)
  if (t == 0){
    const float* hp = h0 + o0;
    #pragma unroll
    for (int j=0;j<8;++j) hl[row][o0+j] = hp[j];
  } else {
    size_t idx = (size_t)(n0+row)*128 + o0;
    float4 ga0 = *(const float4*)(gbuf+idx),          ga1 = *(const float4*)(gbuf+idx+4);
    float4 gb0 = *(const float4*)(gbuf+262144+idx),   gb1 = *(const float4*)(gbuf+262144+idx+4);
    float4 gc0 = *(const float4*)(gbuf+524288+idx),   gc1 = *(const float4*)(gbuf+524288+idx+4);
    float4 gd0 = *(const float4*)(gbuf+786432+idx),   gd1 = *(const float4*)(gbuf+786432+idx+4);
    float4 c0 = *(const float4*)(cell+idx),           c1 = *(const float4*)(cell+idx+4);
    float fgv[8] = {ga0.x,ga0.y,ga0.z,ga0.w,ga1.x,ga1.y,ga1.z,ga1.w};
    float igv[8] = {gb0.x,gb0.y,gb0.z,gb0.w,gb1.x,gb1.y,gb1.z,gb1.w};
    float icv[8] = {gc0.x,gc0.y,gc0.z,gc0.w,gc1.x,gc1.y,gc1.z,gc1.w};
    float ogv[8] = {gd0.x,gd0.y,gd0.z,gd0.w,gd1.x,gd1.y,gd1.z,gd1.w};
    float cv[8]  = {c0.x,c0.y,c0.z,c0.w,c1.x,c1.y,c1.z,c1.w};
    float cl[8], hd[8];
    #pragma unroll
    for (int j=0;j<8;++j){
      cl[j] = cv[j]*sigm(fgv[j]) + sigm(igv[j])*tanhf(icv[j]);
      hd[j] = tanhf(cl[j])*sigm(ogv[j]);
      hl[row][o0+j] = hd[j];
    }
    *(float4*)(cell+idx)   = (float4){cl[0],cl[1],cl[2],cl[3]};
    *(float4*)(cell+idx+4) = (float4){cl[4],cl[5],cl[6],cl[7]};
  }
  __syncthreads();
  // outproj y plane t-1
  if (t >= 1){
    float acc[8];
    float4 b0 = *(const float4*)(bvec+o0), b1 = *(const float4*)(bvec+o0+4);
    acc[0]=b0.x;acc[1]=b0.y;acc[2]=b0.z;acc[3]=b0.w;acc[4]=b1.x;acc[5]=b1.y;acc[6]=b1.z;acc[7]=b1.w;
    for (int k=0;k<128;++k){
      float hv = hl[row][k];
      float4 w0 = *(const float4*)(W + (size_t)k*128 + o0);
      float4 w1 = *(const float4*)(W + (size_t)k*128 + o0 + 4);
      acc[0]+=hv*w0.x; acc[1]+=hv*w0.y; acc[2]+=hv*w0.z; acc[3]+=hv*w0.w;
      acc[4]+=hv*w1.x; acc[5]+=hv*w1.y; acc[6]+=hv*w1.z; acc[7]+=hv*w1.w;
    }
    float* yp = y + (size_t)(t-1)*262144 + (size_t)(n0+row)*128 + o0;
    #pragma unroll
    for (int j=0;j<8;++j) yp[j] = sigm(acc[j]);
  }
  // Phase B: gin bf16 = [X | hidden]
  {
    const float* ap = actors + (size_t)(n0+row)*2560 + xoff + o0;
    float4 a = *(const float4*)ap, bb = *(const float4*)(ap+4);
    unsigned short tmp[8] = {f2bf(a.x),f2bf(a.y),f2bf(a.z),f2bf(a.w),
                             f2bf(bb.x),f2bf(bb.y),f2bf(bb.z),f2bf(bb.w)};
    *(uint4*)&ginb[row*264 + o0] = *(const uint4*)tmp;
    unsigned short tmp2[8];
    #pragma unroll
    for (int j=0;j<8;++j) tmp2[j] = f2bf(hl[row][o0+j]);
    *(uint4*)&ginb[row*264 + 128 + o0] = *(const uint4*)tmp2;
  }
  __syncthreads();
  // Phase C: 4-gate GEMM, wave w -> o in [w*32, w*32+32)
  int w = tid>>6, lane = tid&63, quad = lane>>4, l16 = lane&15;
  int m32 = blockIdx.x>>1, min32 = (blockIdx.x&1)*16 + l16;
  int qp = min32>>3, jp = min32&7;
  for (int g=0; g<4; ++g){
    floatx4 acc0 = {0.f,0.f,0.f,0.f}, acc1 = acc0;
    const unsigned short* wa = WgA + (size_t)g*32768;
    #pragma unroll
    for (int kh=0; kh<8; ++kh){
      short8 bfr = *(const short8*)&ginb[l16*264 + kh*32 + quad*8];
      short8 a0 = *(const short8*)(wa + (size_t)(((w*2+0)*8 + kh)*64 + lane)*8);
      short8 a1 = *(const short8*)(wa + (size_t)(((w*2+1)*8 + kh)*64 + lane)*8);
      acc0 = MFMA16(a0, bfr, acc0);
      acc1 = MFMA16(a1, bfr, acc1);
    }
    float ps = 0.f, pd = 0.f;
    unsigned short* wb = WhB + (size_t)(g*8 + w*2)*32768 + m32*512 + qp*128 + jp;
    const float* agp = ag + g*256;
    #pragma unroll
    for (int i=0;i<2;++i){
      floatx4 ac = i ? acc1 : acc0;
      #pragma unroll
      for (int r=0;r<4;++r){
        int o = w*32 + i*16 + quad*4 + r;
        float v = ac[r];
        ps += v*agp[o]; pd += v*agp[128+o];
        wb[i*32768 + (quad*4+r)*8] = f2bf(v);
      }
    }
    ps += __shfl_down(ps,32); ps += __shfl_down(ps,16);
    pd += __shfl_down(pd,32); pd += __shfl_down(pd,16);
    if (lane < 16){ sredS[g][w][l16] = ps; sredD[g][w][l16] = pd; }
  }
  __syncthreads();
  if (tid < 128){
    int g = tid>>5, which = (tid>>4)&1, n = tid&15;
    float s;
    if (which) s = sredD[g][0][n]+sredD[g][1][n]+sredD[g][2][n]+sredD[g][3][n];
    else       s = sredS[g][0][n]+sredS[g][1][n]+sredS[g][2][n]+sredS[g][3][n];
    (which ? s_dst : s_src)[g*2048 + n0 + n] = s;
  }
}

// ---- fused masked-softmax + PV: 512 thr = 8 m-waves (m-256 each), 16 rows ----
// 2 blocks/CU x 8 waves = 4 waves/SIMD: latency hiding for L2 B-fragment loads.
__global__ __launch_bounds__(512) void attn_kernel(const unsigned char* __restrict__ bmb,
    const unsigned short* __restrict__ WhB, const float* __restrict__ s_src,
    const float* __restrict__ s_dst, float* __restrict__ gout, int t){
  __shared__ float obuf[4][16][132];   // 33.8 KB
  __shared__ float zpart[8][16];
  int g = blockIdx.y, n0 = blockIdx.x*16, tid = threadIdx.x;
  int w = tid>>6, lane = tid&63, quad = lane>>4, l16 = lane&15;
  float srcv = s_src[g*2048 + n0 + l16];
  const float* sd = s_dst + g*2048;
  // preload lane's 32-byte mask strip (row n0+l16, m in [w*256, w*256+256))
  const unsigned char* mrow = bmb + ((size_t)t*2048 + n0 + l16)*256 + w*32;
  uint4 q0 = *(const uint4*)mrow, q1 = *(const uint4*)(mrow+16);
  unsigned mwd[8] = {q0.x,q0.y,q0.z,q0.w, q1.x,q1.y,q1.z,q1.w};
  const unsigned short* wb = WhB + (size_t)g*262144;
  float z0 = 0.f;
  floatx4 acc[8];
  #pragma unroll
  for (int j=0;j<8;++j) acc[j] = (floatx4){0.f,0.f,0.f,0.f};
  #pragma unroll
  for (int c=0; c<8; ++c){
    int mk = w*256 + c*32 + quad*8;
    float4 sa = *(const float4*)(sd + mk);
    float4 sb = *(const float4*)(sd + mk + 4);
    unsigned mb = (mwd[c] >> (quad*8)) & 0xffu;
    float sv[8] = {sa.x,sa.y,sa.z,sa.w,sb.x,sb.y,sb.z,sb.w};
    short8 A0;
    #pragma unroll
    for (int j=0;j<8;++j){
      float s = srcv + sv[j];
      s = s > 0.f ? s : 0.2f*s;                    // leaky_relu
      float p = ((mb >> j) & 1u) ? __expf(s) : 0.f;
      z0 += p;
      A0[j] = (short)f2bf(p);
    }
    const unsigned short* bp = wb + (size_t)(w*8 + c)*512 + lane*8;
    #pragma unroll
    for (int o16=0; o16<8; ++o16){
      short8 bfr = *(const short8*)(bp + (size_t)o16*32768);
      acc[o16] = MFMA16(A0, bfr, acc[o16]);
    }
  }
  z0 += __shfl_down(z0,32); z0 += __shfl_down(z0,16);
  if (lane < 16) zpart[w][l16] = z0;
  if (w < 4){
    #pragma unroll
    for (int o16=0;o16<8;++o16)
      #pragma unroll
      for (int r=0;r<4;++r)
        obuf[w][quad*4+r][o16*16+l16] = acc[o16][r];
  }
  __syncthreads();
  if (w >= 4){
    #pragma unroll
    for (int o16=0;o16<8;++o16)
      #pragma unroll
      for (int r=0;r<4;++r)
        obuf[w-4][quad*4+r][o16*16+l16] += acc[o16][r];
  }
  __syncthreads();
  { // normalize + elu + store: 4 floats/thread
    int row = tid>>5, c0 = (tid&31)*4;
    float z = zpart[0][row]+zpart[1][row]+zpart[2][row]+zpart[3][row]
            + zpart[4][row]+zpart[5][row]+zpart[6][row]+zpart[7][row];
    float inv = 1.f / z;
    float* go = gout + (size_t)g*262144 + (size_t)(n0+row)*128 + c0;
    #pragma unroll
    for (int j=0;j<4;++j){
      float v = (obuf[0][row][c0+j] + obuf[1][row][c0+j]
               + obuf[2][row][c0+j] + obuf[3][row][c0+j]) * inv;
      go[j] = v > 0.f ? v : __expf(v) - 1.f;       // elu
    }
  }
}

// ---- final gate + y3 + all 3 temporal conv layers; 4 rows/block, 512 blocks ----
__global__ __launch_bounds__(256) void convgate_kernel(const float* __restrict__ gbuf,
    const float* __restrict__ cell, const float* __restrict__ W, const float* __restrict__ bvec,
    const float* __restrict__ y, const float* __restrict__ cwT, const float* __restrict__ cb,
    float* __restrict__ out){
  __shared__ float hl[4][128];
  __shared__ float ylds[4][128][4];
  int tid = threadIdx.x;
  int r = tid >> 6, oc = (tid & 63)*2;
  int n = blockIdx.x*4 + r;
  size_t idx = (size_t)n*128 + oc;
  { // gate_3
    float2 g0 = *(const float2*)(gbuf+idx),        g1 = *(const float2*)(gbuf+262144+idx);
    float2 g2 = *(const float2*)(gbuf+524288+idx), g3 = *(const float2*)(gbuf+786432+idx);
    float2 cv = *(const float2*)(cell+idx);
    float fg[2]={g0.x,g0.y}, ig[2]={g1.x,g1.y}, ic[2]={g2.x,g2.y}, og[2]={g3.x,g3.y};
    float cc[2]={cv.x,cv.y};
    #pragma unroll
    for (int j=0;j<2;++j){
      float cl = cc[j]*sigm(fg[j]) + sigm(ig[j])*tanhf(ic[j]);
      hl[r][oc+j] = tanhf(cl)*sigm(og[j]);
    }
  }
  {
    float2 y0 = *(const float2*)(y+idx), y1 = *(const float2*)(y+262144+idx),
           y2 = *(const float2*)(y+524288+idx);
    float a0[2]={y0.x,y0.y}, a1[2]={y1.x,y1.y}, a2[2]={y2.x,y2.y};
    #pragma unroll
    for (int j=0;j<2;++j){
      ylds[r][oc+j][0]=a0[j]; ylds[r][oc+j][1]=a1[j]; ylds[r][oc+j][2]=a2[j];
    }
  }
  __syncthreads();
  { // y3 outproj
    float2 bb = *(const float2*)(bvec+oc);
    float acc[2] = {bb.x, bb.y};
    const float* hr = hl[r];
    for (int k=0;k<128;++k){
      float hv = hr[k];
      float2 wv = *(const float2*)(W + (size_t)k*128 + oc);
      acc[0]+=hv*wv.x; acc[1]+=hv*wv.y;
    }
    #pragma unroll
    for (int j=0;j<2;++j) ylds[r][oc+j][3] = sigm(acc[j]);
  }
  __syncthreads();
  { // layer 0: 4 -> 3
    float a0[2]={0,0}, a1[2]={0,0}, a2[2]={0,0};
    for (int k=0;k<128;++k){
      float2 w0 = *(const float2*)(cwT + k*256 + oc);
      float2 w1 = *(const float2*)(cwT + k*256 + 128 + oc);
      float4 yv = *(const float4*)&ylds[r][k][0];
      float wa[2]={w0.x,w0.y}, wb2[2]={w1.x,w1.y};
      #pragma unroll
      for (int j=0;j<2;++j){
        a0[j] += yv.x*wa[j] + yv.y*wb2[j];
        a1[j] += yv.y*wa[j] + yv.z*wb2[j];
        a2[j] += yv.z*wa[j] + yv.w*wb2[j];
      }
    }
    float2 bb = *(const float2*)(cb+oc);
    float bbv[2]={bb.x,bb.y};
    __syncthreads();
    #pragma unroll
    for (int j=0;j<2;++j){
      ylds[r][oc+j][0]=a0[j]+bbv[j]; ylds[r][oc+j][1]=a1[j]+bbv[j]; ylds[r][oc+j][2]=a2[j]+bbv[j];
    }
    __syncthreads();
  }
  { // layer 1: 3 -> 2
    float a0[2]={0,0}, a1[2]={0,0};
    for (int k=0;k<128;++k){
      float2 w0 = *(const float2*)(cwT + 32768 + k*256 + oc);
      float2 w1 = *(const float2*)(cwT + 32768 + k*256 + 128 + oc);
      float4 yv = *(const float4*)&ylds[r][k][0];
      float wa[2]={w0.x,w0.y}, wb2[2]={w1.x,w1.y};
      #pragma unroll
      for (int j=0;j<2;++j){
        a0[j] += yv.x*wa[j] + yv.y*wb2[j];
        a1[j] += yv.y*wa[j] + yv.z*wb2[j];
      }
    }
    float2 bb = *(const float2*)(cb+128+oc);
    float bbv[2]={bb.x,bb.y};
    __syncthreads();
    #pragma unroll
    for (int j=0;j<2;++j){
      ylds[r][oc+j][0]=a0[j]+bbv[j]; ylds[r][oc+j][1]=a1[j]+bbv[j];
    }
    __syncthreads();
  }
  { // layer 2: 2 -> 1
    float a0[2]={0,0};
    for (int k=0;k<128;++k){
      float2 w0 = *(const float2*)(cwT + 65536 + k*256 + oc);
      float2 w1 = *(const float2*)(cwT + 65536 + k*256 + 128 + oc);
      float4 yv = *(const float4*)&ylds[r][k][0];
      a0[0] += yv.x*w0.x + yv.y*w1.x;
      a0[1] += yv.x*w0.y + yv.y*w1.y;
    }
    float2 bb = *(const float2*)(cb+256+oc);
    float2 res = {a0[0]+bb.x, a0[1]+bb.y};
    *(float2*)(out+idx) = res;
  }
}

extern "C" void kernel_launch(void* const* d_in, const int* in_sizes, int n_in,
                              void* d_out, int out_size, void* d_ws, size_t ws_size,
                              hipStream_t stream) {
  const float* actors = (const float*)d_in[0];
  const int*   adj    = (const int*)d_in[1];
  const float* Wg     = (const float*)d_in[2];
  const float* ag     = (const float*)d_in[3];
  const float* W      = (const float*)d_in[4];
  const float* b      = (const float*)d_in[5];
  const float* h0     = (const float*)d_in[6];
  const float* cw     = (const float*)d_in[7];
  const float* cb     = (const float*)d_in[8];
  float* out = (float*)d_out;

  char* ws = (char*)d_ws;
  unsigned long long* bm = (unsigned long long*)ws;                  // 2 MB
  float* cell          = (float*)(ws + (size_t)(2u<<20));            // 1 MB
  unsigned short* WgA  = (unsigned short*)(ws + (size_t)(3u<<20));   // 256 KB bf16 swizzled
  float* cwT           = (float*)(ws + (size_t)3407872);             // 384 KB
  float* s_src         = (float*)(ws + (size_t)3932160);             // 32 KB
  float* s_dst         = (float*)(ws + (size_t)3932160 + 32768);     // 32 KB
  unsigned short* WhB  = (unsigned short*)(ws + (size_t)(4u<<20));   // 2 MB bf16 swizzled
  float* gbuf          = (float*)(ws + (size_t)(7u<<20));            // 4 MB [g][n][o]
  float* yplanes       = (float*)(ws + (size_t)(11u<<20));           // 3 MB [t][n][o]

  const int XI[4] = {4, 9, 14, 19};

  prep_kernel<<<3776, 256, 0, stream>>>(actors, Wg, cw, adj, cell, WgA, cwT, bm);
  for (int t=0; t<4; ++t){
    gatewh_kernel<<<128, 256, 0, stream>>>(actors, gbuf, cell, h0, W, b, WgA, ag,
                                           yplanes, WhB, s_src, s_dst, XI[t]*128, t);
    attn_kernel<<<dim3(128,4), 512, 0, stream>>>((const unsigned char*)bm, WhB,
                                                 s_src, s_dst, gbuf, t);
  }
  convgate_kernel<<<512, 256, 0, stream>>>(gbuf, cell, W, b, yplanes, cwT, cb, out);
}

// Round 7
// 598.739 us; speedup vs baseline: 1.1081x; 1.0023x over previous
//
#include <hip/hip_runtime.h>

typedef __attribute__((ext_vector_type(8))) short short8;
typedef __attribute__((ext_vector_type(4))) float floatx4;

#define MFMA16(a,b,c) __builtin_amdgcn_mfma_f32_16x16x32_bf16(a,b,c,0,0,0)

__device__ __forceinline__ unsigned short f2bf(float f){
  unsigned u = __float_as_uint(f);
  u += 0x7fffu + ((u >> 16) & 1u);
  return (unsigned short)(u >> 16);
}
__device__ __forceinline__ float sigm(float x){ return 1.f/(1.f+__expf(-x)); }

// WhB/WgA swizzled B/A-fragment layouts:
//  element (o, m):  flat = (o>>4)*32768 + (m>>5)*512 + (((m>>3)&3)*16 + (o&15))*8 + (m&7)
//  -> a wave's 64 lanes (lane = quad*16+l16) read 1KB contiguous per (o16, m32) chunk.

// ---- fused prep: cell init + WgA swizzle + cwT transpose + adjacency bitmasks ----
__global__ __launch_bounds__(256) void prep_kernel(const float* __restrict__ actors,
    const float* __restrict__ Wg, const float* __restrict__ cw, const int* __restrict__ adj,
    float* __restrict__ cell, unsigned short* __restrict__ WgA, float* __restrict__ cwT,
    unsigned long long* __restrict__ bm){
  int bid = blockIdx.x;
  if (bid < 1024){
    int idx = bid*256 + threadIdx.x;
    int n = idx >> 7, c = idx & 127;
    cell[idx] = actors[(size_t)n*2560 + c];
  } else if (bid < 1536){
    int e = (bid-1024)*256 + threadIdx.x;            // 131072
    int g = e >> 15, o = (e >> 8) & 127, k = e & 255;
    unsigned short v = f2bf(Wg[(size_t)g*32768 + k*128 + o]);
    int off = ((o>>4)*8 + (k>>5))*512 + (((k>>3)&3)*16 + (o&15))*8 + (k&7);
    WgA[(size_t)g*32768 + off] = v;
  } else if (bid < 1728){
    int e = (bid-1536)*256 + threadIdx.x;            // 49152
    int l = e >> 14, rr = e & 16383, k = rr >> 7, o = rr & 127;
    cwT[(size_t)l*32768 + k*256 + o]       = cw[(size_t)l*32768 + o*256 + k*2];
    cwT[(size_t)l*32768 + k*256 + 128 + o] = cw[(size_t)l*32768 + o*256 + k*2 + 1];
  } else {
    const int E[4] = {0,4,9,14};
    int mb = bid - 1728;                             // 2048 blocks
    int t = mb & 3, nblk = mb >> 2;
    int wv = threadIdx.x >> 6, lane = threadIdx.x & 63;
    int n = nblk*4 + wv;
    const int* row = adj + (size_t)n*40960 + (size_t)E[t]*2048;
    unsigned long long* outp = bm + ((size_t)t*2048 + n)*32;
    for (int it=0; it<32; ++it){
      unsigned long long bal = __ballot(row[it*64 + lane] > 0);
      if (lane == 0) outp[it] = bal;
    }
  }
}

// ---- fused: LSTM gate + y outproj + 4-gate Wh GEMM ----
// grid 256 = (tile 0..127) x (o-half); 512 threads = 8 waves.
// spart layout: [(ohalf*2+which)*4+g][2048], which: 0=src 1=dst.
__global__ __launch_bounds__(512) void gatewh_kernel(const float* __restrict__ actors,
    const float* __restrict__ gbuf, float* __restrict__ cell, const float* __restrict__ h0,
    const float* __restrict__ W, const float* __restrict__ bvec,
    const unsigned short* __restrict__ WgA, const float* __restrict__ ag,
    float* __restrict__ y, unsigned short* __restrict__ WhB,
    float* __restrict__ spart, int xoff, int t){
  __shared__ float hl[16][132];
  __shared__ __align__(16) unsigned short ginb[16*264];
  __shared__ float sredS[4][4][16], sredD[4][4][16];
  int bx = blockIdx.x;
  int tile = bx >> 1, ohalf = bx & 1;
  int n0 = tile*16, tid = threadIdx.x;
  int row = tid>>5, q = tid&31;
  // Phase A: hidden (+cell from previous gates); 4 cols/thread
  {
    int o0 = q*4;
    if (t == 0){
      *(float4*)&hl[row][o0] = *(const float4*)(h0 + o0);
    } else {
      size_t idx = (size_t)(n0+row)*128 + o0;
      float4 ga = *(const float4*)(gbuf+idx);
      float4 gb = *(const float4*)(gbuf+262144+idx);
      float4 gc = *(const float4*)(gbuf+524288+idx);
      float4 gd = *(const float4*)(gbuf+786432+idx);
      float4 cv = *(const float4*)(cell+idx);
      float fg[4]={ga.x,ga.y,ga.z,ga.w}, ig[4]={gb.x,gb.y,gb.z,gb.w};
      float ic[4]={gc.x,gc.y,gc.z,gc.w}, og[4]={gd.x,gd.y,gd.z,gd.w};
      float cc[4]={cv.x,cv.y,cv.z,cv.w};
      float clv[4];
      #pragma unroll
      for (int j=0;j<4;++j){
        clv[j] = cc[j]*sigm(fg[j]) + sigm(ig[j])*tanhf(ic[j]);
        hl[row][o0+j] = tanhf(clv[j])*sigm(og[j]);
      }
      if (ohalf == 0)
        *(float4*)(cell+idx) = (float4){clv[0],clv[1],clv[2],clv[3]};
    }
  }
  __syncthreads();
  // outproj y plane t-1 (2 cols/thread, this block's o-half)
  if (t >= 1){
    int oc = ohalf*64 + q*2;
    float2 bb2 = *(const float2*)(bvec+oc);
    float a0 = bb2.x, a1 = bb2.y;
    const float* hr = hl[row];
    for (int k=0;k<128;++k){
      float hv = hr[k];
      float2 wv = *(const float2*)(W + (size_t)k*128 + oc);
      a0 += hv*wv.x; a1 += hv*wv.y;
    }
    float* yp = y + (size_t)(t-1)*262144 + (size_t)(n0+row)*128 + oc;
    yp[0] = sigm(a0); yp[1] = sigm(a1);
  }
  // Phase B: gin bf16 = [X | hidden]
  if (q < 16){
    const float* ap = actors + (size_t)(n0+row)*2560 + xoff + q*8;
    float4 a = *(const float4*)ap, bb = *(const float4*)(ap+4);
    unsigned short tmp[8] = {f2bf(a.x),f2bf(a.y),f2bf(a.z),f2bf(a.w),
                             f2bf(bb.x),f2bf(bb.y),f2bf(bb.z),f2bf(bb.w)};
    *(uint4*)&ginb[row*264 + q*8] = *(const uint4*)tmp;
  } else {
    int c0 = (q-16)*8;
    unsigned short tmp[8];
    #pragma unroll
    for (int j=0;j<8;++j) tmp[j] = f2bf(hl[row][c0+j]);
    *(uint4*)&ginb[row*264 + 128 + c0] = *(const uint4*)tmp;
  }
  __syncthreads();
  // Phase C: 8 waves x 2 (g,o16) chunks; this block covers o-half
  int w = tid>>6, lane = tid&63, quad = lane>>4, l16 = lane&15;
  int m32 = tile>>1, min32 = (tile&1)*16 + l16;
  int qp = min32>>3, jp = min32&7;
  #pragma unroll
  for (int ci=0; ci<2; ++ci){
    int cidx = w*2 + ci;                 // 0..15
    int g = cidx>>2, o16q = cidx&3, o16 = ohalf*4 + o16q;
    floatx4 acc = {0.f,0.f,0.f,0.f};
    const unsigned short* wa = WgA + (size_t)g*32768;
    #pragma unroll
    for (int kh=0; kh<8; ++kh){
      short8 bfr = *(const short8*)&ginb[l16*264 + kh*32 + quad*8];
      short8 a0 = *(const short8*)(wa + (size_t)((o16*8 + kh)*64 + lane)*8);
      acc = MFMA16(a0, bfr, acc);
    }
    float ps = 0.f, pd = 0.f;
    unsigned short* wb = WhB + (size_t)(g*8 + o16)*32768 + m32*512 + qp*128 + jp;
    const float* agp = ag + g*256;
    #pragma unroll
    for (int r=0;r<4;++r){
      int o = o16*16 + quad*4 + r;
      float v = acc[r];
      ps += v*agp[o]; pd += v*agp[128+o];
      wb[(quad*4+r)*8] = f2bf(v);
    }
    ps += __shfl_down(ps,32); ps += __shfl_down(ps,16);
    pd += __shfl_down(pd,32); pd += __shfl_down(pd,16);
    if (lane < 16){ sredS[g][o16q][l16] = ps; sredD[g][o16q][l16] = pd; }
  }
  __syncthreads();
  if (tid < 128){
    int g = tid>>5, which = (tid>>4)&1, n = tid&15;
    float s;
    if (which) s = sredD[g][0][n]+sredD[g][1][n]+sredD[g][2][n]+sredD[g][3][n];
    else       s = sredS[g][0][n]+sredS[g][1][n]+sredS[g][2][n]+sredS[g][3][n];
    spart[(size_t)((ohalf*2 + which)*4 + g)*2048 + n0 + n] = s;
  }
}

// ---- fused masked-softmax + PV: 512 thr = 8 m-waves, 32 rows (dual A-chain) ----
// Halves L2 WhB traffic vs 16-row; 8 waves/block keeps 2 waves/SIMD.
__global__ __launch_bounds__(512) void attn_kernel(const unsigned char* __restrict__ bmb,
    const unsigned short* __restrict__ WhB, const float* __restrict__ spart,
    float* __restrict__ gout, int t){
  __shared__ float obuf[4][32][132];   // 67.6 KB
  __shared__ float zpart[8][32];
  int g = blockIdx.y, n0 = blockIdx.x*32, tid = threadIdx.x;
  int w = tid>>6, lane = tid&63, quad = lane>>4, l16 = lane&15;
  const float* sS0 = spart + (size_t)(0 + g)*2048;
  const float* sD0 = spart + (size_t)(4 + g)*2048;
  const float* sS1 = spart + (size_t)(8 + g)*2048;
  const float* sD1 = spart + (size_t)(12 + g)*2048;
  float srcv0 = sS0[n0 + l16]      + sS1[n0 + l16];
  float srcv1 = sS0[n0 + 16 + l16] + sS1[n0 + 16 + l16];
  // preload both rows' 32-byte mask strips (m in [w*256, w*256+256))
  const unsigned char* mr0 = bmb + ((size_t)t*2048 + n0 + l16)*256 + w*32;
  const unsigned char* mr1 = mr0 + 16*256;
  uint4 q0 = *(const uint4*)mr0, q1 = *(const uint4*)(mr0+16);
  uint4 r0 = *(const uint4*)mr1, r1 = *(const uint4*)(mr1+16);
  unsigned mwd0[8] = {q0.x,q0.y,q0.z,q0.w, q1.x,q1.y,q1.z,q1.w};
  unsigned mwd1[8] = {r0.x,r0.y,r0.z,r0.w, r1.x,r1.y,r1.z,r1.w};
  const unsigned short* wb = WhB + (size_t)g*262144;
  float z0 = 0.f, z1 = 0.f;
  floatx4 acc0[8], acc1[8];
  #pragma unroll
  for (int j=0;j<8;++j){ acc0[j] = (floatx4){0.f,0.f,0.f,0.f}; acc1[j] = acc0[j]; }
  #pragma unroll
  for (int c=0; c<8; ++c){
    int mk = w*256 + c*32 + quad*8;
    float4 sa0 = *(const float4*)(sD0 + mk), sb0 = *(const float4*)(sD0 + mk + 4);
    float4 sa1 = *(const float4*)(sD1 + mk), sb1 = *(const float4*)(sD1 + mk + 4);
    unsigned mb0 = (mwd0[c] >> (quad*8)) & 0xffu;
    unsigned mb1 = (mwd1[c] >> (quad*8)) & 0xffu;
    float sv[8] = {sa0.x+sa1.x, sa0.y+sa1.y, sa0.z+sa1.z, sa0.w+sa1.w,
                   sb0.x+sb1.x, sb0.y+sb1.y, sb0.z+sb1.z, sb0.w+sb1.w};
    short8 A0, A1;
    #pragma unroll
    for (int j=0;j<8;++j){
      float s0 = srcv0 + sv[j];
      s0 = s0 > 0.f ? s0 : 0.2f*s0;                // leaky_relu
      float p0 = ((mb0 >> j) & 1u) ? __expf(s0) : 0.f;
      z0 += p0;
      A0[j] = (short)f2bf(p0);
      float s1 = srcv1 + sv[j];
      s1 = s1 > 0.f ? s1 : 0.2f*s1;
      float p1 = ((mb1 >> j) & 1u) ? __expf(s1) : 0.f;
      z1 += p1;
      A1[j] = (short)f2bf(p1);
    }
    const unsigned short* bp = wb + (size_t)(w*8 + c)*512 + lane*8;
    #pragma unroll
    for (int o16=0; o16<8; ++o16){
      short8 bfr = *(const short8*)(bp + (size_t)o16*32768);
      acc0[o16] = MFMA16(A0, bfr, acc0[o16]);
      acc1[o16] = MFMA16(A1, bfr, acc1[o16]);
    }
  }
  z0 += __shfl_down(z0,32); z0 += __shfl_down(z0,16);
  z1 += __shfl_down(z1,32); z1 += __shfl_down(z1,16);
  if (lane < 16){ zpart[w][l16] = z0; zpart[w][16+l16] = z1; }
  if (w < 4){
    #pragma unroll
    for (int o16=0;o16<8;++o16)
      #pragma unroll
      for (int r=0;r<4;++r){
        obuf[w][quad*4+r][o16*16+l16]      = acc0[o16][r];
        obuf[w][16+quad*4+r][o16*16+l16]   = acc1[o16][r];
      }
  }
  __syncthreads();
  if (w >= 4){
    #pragma unroll
    for (int o16=0;o16<8;++o16)
      #pragma unroll
      for (int r=0;r<4;++r){
        obuf[w-4][quad*4+r][o16*16+l16]    += acc0[o16][r];
        obuf[w-4][16+quad*4+r][o16*16+l16] += acc1[o16][r];
      }
  }
  __syncthreads();
  { // normalize + elu + store: 8 floats/thread
    int row = tid>>4, c0 = (tid&15)*8;
    float z = zpart[0][row]+zpart[1][row]+zpart[2][row]+zpart[3][row]
            + zpart[4][row]+zpart[5][row]+zpart[6][row]+zpart[7][row];
    float inv = 1.f / z;
    float* go = gout + (size_t)g*262144 + (size_t)(n0+row)*128 + c0;
    #pragma unroll
    for (int j=0;j<8;++j){
      float v = (obuf[0][row][c0+j] + obuf[1][row][c0+j]
               + obuf[2][row][c0+j] + obuf[3][row][c0+j]) * inv;
      go[j] = v > 0.f ? v : __expf(v) - 1.f;       // elu
    }
  }
}

// ---- final gate + y3 + all 3 temporal conv layers; 4 rows/block, 512 blocks ----
__global__ __launch_bounds__(256) void convgate_kernel(const float* __restrict__ gbuf,
    const float* __restrict__ cell, const float* __restrict__ W, const float* __restrict__ bvec,
    const float* __restrict__ y, const float* __restrict__ cwT, const float* __restrict__ cb,
    float* __restrict__ out){
  __shared__ float hl[4][128];
  __shared__ float ylds[4][128][4];
  int tid = threadIdx.x;
  int r = tid >> 6, oc = (tid & 63)*2;
  int n = blockIdx.x*4 + r;
  size_t idx = (size_t)n*128 + oc;
  { // gate_3
    float2 g0 = *(const float2*)(gbuf+idx),        g1 = *(const float2*)(gbuf+262144+idx);
    float2 g2 = *(const float2*)(gbuf+524288+idx), g3 = *(const float2*)(gbuf+786432+idx);
    float2 cv = *(const float2*)(cell+idx);
    float fg[2]={g0.x,g0.y}, ig[2]={g1.x,g1.y}, ic[2]={g2.x,g2.y}, og[2]={g3.x,g3.y};
    float cc[2]={cv.x,cv.y};
    #pragma unroll
    for (int j=0;j<2;++j){
      float cl = cc[j]*sigm(fg[j]) + sigm(ig[j])*tanhf(ic[j]);
      hl[r][oc+j] = tanhf(cl)*sigm(og[j]);
    }
  }
  {
    float2 y0 = *(const float2*)(y+idx), y1 = *(const float2*)(y+262144+idx),
           y2 = *(const float2*)(y+524288+idx);
    float a0[2]={y0.x,y0.y}, a1[2]={y1.x,y1.y}, a2[2]={y2.x,y2.y};
    #pragma unroll
    for (int j=0;j<2;++j){
      ylds[r][oc+j][0]=a0[j]; ylds[r][oc+j][1]=a1[j]; ylds[r][oc+j][2]=a2[j];
    }
  }
  __syncthreads();
  { // y3 outproj
    float2 bb = *(const float2*)(bvec+oc);
    float acc[2] = {bb.x, bb.y};
    const float* hr = hl[r];
    for (int k=0;k<128;++k){
      float hv = hr[k];
      float2 wv = *(const float2*)(W + (size_t)k*128 + oc);
      acc[0]+=hv*wv.x; acc[1]+=hv*wv.y;
    }
    #pragma unroll
    for (int j=0;j<2;++j) ylds[r][oc+j][3] = sigm(acc[j]);
  }
  __syncthreads();
  { // layer 0: 4 -> 3
    float a0[2]={0,0}, a1[2]={0,0}, a2[2]={0,0};
    for (int k=0;k<128;++k){
      float2 w0 = *(const float2*)(cwT + k*256 + oc);
      float2 w1 = *(const float2*)(cwT + k*256 + 128 + oc);
      float4 yv = *(const float4*)&ylds[r][k][0];
      float wa[2]={w0.x,w0.y}, wb2[2]={w1.x,w1.y};
      #pragma unroll
      for (int j=0;j<2;++j){
        a0[j] += yv.x*wa[j] + yv.y*wb2[j];
        a1[j] += yv.y*wa[j] + yv.z*wb2[j];
        a2[j] += yv.z*wa[j] + yv.w*wb2[j];
      }
    }
    float2 bb = *(const float2*)(cb+oc);
    float bbv[2]={bb.x,bb.y};
    __syncthreads();
    #pragma unroll
    for (int j=0;j<2;++j){
      ylds[r][oc+j][0]=a0[j]+bbv[j]; ylds[r][oc+j][1]=a1[j]+bbv[j]; ylds[r][oc+j][2]=a2[j]+bbv[j];
    }
    __syncthreads();
  }
  { // layer 1: 3 -> 2
    float a0[2]={0,0}, a1[2]={0,0};
    for (int k=0;k<128;++k){
      float2 w0 = *(const float2*)(cwT + 32768 + k*256 + oc);
      float2 w1 = *(const float2*)(cwT + 32768 + k*256 + 128 + oc);
      float4 yv = *(const float4*)&ylds[r][k][0];
      float wa[2]={w0.x,w0.y}, wb2[2]={w1.x,w1.y};
      #pragma unroll
      for (int j=0;j<2;++j){
        a0[j] += yv.x*wa[j] + yv.y*wb2[j];
        a1[j] += yv.y*wa[j] + yv.z*wb2[j];
      }
    }
    float2 bb = *(const float2*)(cb+128+oc);
    float bbv[2]={bb.x,bb.y};
    __syncthreads();
    #pragma unroll
    for (int j=0;j<2;++j){
      ylds[r][oc+j][0]=a0[j]+bbv[j]; ylds[r][oc+j][1]=a1[j]+bbv[j];
    }
    __syncthreads();
  }
  { // layer 2: 2 -> 1
    float a0[2]={0,0};
    for (int k=0;k<128;++k){
      float2 w0 = *(const float2*)(cwT + 65536 + k*256 + oc);
      float2 w1 = *(const float2*)(cwT + 65536 + k*256 + 128 + oc);
      float4 yv = *(const float4*)&ylds[r][k][0];
      a0[0] += yv.x*w0.x + yv.y*w1.x;
      a0[1] += yv.x*w0.y + yv.y*w1.y;
    }
    float2 bb = *(const float2*)(cb+256+oc);
    float2 res = {a0[0]+bb.x, a0[1]+bb.y};
    *(float2*)(out+idx) = res;
  }
}

extern "C" void kernel_launch(void* const* d_in, const int* in_sizes, int n_in,
                              void* d_out, int out_size, void* d_ws, size_t ws_size,
                              hipStream_t stream) {
  const float* actors = (const float*)d_in[0];
  const int*   adj    = (const int*)d_in[1];
  const float* Wg     = (const float*)d_in[2];
  const float* ag     = (const float*)d_in[3];
  const float* W      = (const float*)d_in[4];
  const float* b      = (const float*)d_in[5];
  const float* h0     = (const float*)d_in[6];
  const float* cw     = (const float*)d_in[7];
  const float* cb     = (const float*)d_in[8];
  float* out = (float*)d_out;

  char* ws = (char*)d_ws;
  unsigned long long* bm = (unsigned long long*)ws;                  // 2 MB
  float* cell          = (float*)(ws + (size_t)(2u<<20));            // 1 MB
  unsigned short* WgA  = (unsigned short*)(ws + (size_t)(3u<<20));   // 256 KB bf16 swizzled
  float* cwT           = (float*)(ws + (size_t)3407872);             // 384 KB
  float* spart         = (float*)(ws + (size_t)3932160);             // 128 KB [16][2048]
  unsigned short* WhB  = (unsigned short*)(ws + (size_t)(4u<<20));   // 2 MB bf16 swizzled
  float* gbuf          = (float*)(ws + (size_t)(7u<<20));            // 4 MB [g][n][o]
  float* yplanes       = (float*)(ws + (size_t)(11u<<20));           // 3 MB [t][n][o]

  const int XI[4] = {4, 9, 14, 19};

  prep_kernel<<<3776, 256, 0, stream>>>(actors, Wg, cw, adj, cell, WgA, cwT, bm);
  for (int t=0; t<4; ++t){
    gatewh_kernel<<<256, 512, 0, stream>>>(actors, gbuf, cell, h0, W, b, WgA, ag,
                                           yplanes, WhB, spart, XI[t]*128, t);
    attn_kernel<<<dim3(64,4), 512, 0, stream>>>((const unsigned char*)bm, WhB,
                                                spart, gbuf, t);
  }
  convgate_kernel<<<512, 256, 0, stream>>>(gbuf, cell, W, b, yplanes, cwT, cb, out);
}